// Round 10
// baseline (131.180 us; speedup 1.0000x reference)
//
#include <hip/hip_runtime.h>
#include <hip/hip_bf16.h>
#include <stdint.h>

#define NQ 10
#define DIMQ 1024
#define NLAYERS 4
#define BATCH 4096
#define NOUT 16

#define GM 4096
#define GN 2048
#define GK 1024

using f32x4 = __attribute__((ext_vector_type(4))) float;
using s16x8 = __attribute__((ext_vector_type(8))) short;

__device__ __forceinline__ float bf2f(unsigned short u) {
  union { unsigned int i; float f; } v; v.i = ((unsigned int)u) << 16; return v.f;
}
__device__ __forceinline__ unsigned short f2bf(float f) {
  union { float f; unsigned int i; } v; v.f = f;
  unsigned int x = v.i;
  return (unsigned short)((x + 0x7fffu + ((x >> 16) & 1u)) >> 16);  // RNE, finite inputs
}

// broadcast lane i's float to all lanes as a wave-uniform (SGPR) value.
#define RL(v, i) __int_as_float(__builtin_amdgcn_readlane(__float_as_int(v), (i)))

// pack (R,I) -> u32 of 2 bf16 (round-half-up via +0x8000 then byte-perm).
__device__ __forceinline__ unsigned int pkri(float r, float i) {
  unsigned int ur = __float_as_uint(r) + 0x8000u;
  unsigned int ui = __float_as_uint(i) + 0x8000u;
  // out bytes [3..0] = [i.b3, i.b2, r.b3, r.b2]
  return __builtin_amdgcn_perm(ui, ur, 0x07060302u);
}
__device__ __forceinline__ float upR(unsigned int p) { return __uint_as_float(p << 16); }
__device__ __forceinline__ float upI(unsigned int p) { return __uint_as_float(p & 0xffff0000u); }

// cross-lane xor-move of a packed u32; masks 1,2 ride the VALU pipe (DPP
// quad_perm), larger masks use ds bpermute (__shfl_xor). m is compile-time
// after unrolling.
__device__ __forceinline__ unsigned int lmove(unsigned int v, int m) {
  if (m == 1) return (unsigned int)__builtin_amdgcn_mov_dpp((int)v, 0xB1, 0xF, 0xF, false);
  if (m == 2) return (unsigned int)__builtin_amdgcn_mov_dpp((int)v, 0x4E, 0xF, 0xF, false);
  return (unsigned int)__shfl_xor((int)v, m, 64);
}

// ------------------------------------------------------------- normalize ---
__global__ __launch_bounds__(256) void normalize_rows(const float* __restrict__ X,
                                                      unsigned short* __restrict__ Xn) {
  int lane = threadIdx.x & 63;
  int row = blockIdx.x * 4 + (threadIdx.x >> 6);
  const float* xr = X + (size_t)row * DIMQ;
  float4 v[4];
  float ss = 0.f;
  #pragma unroll
  for (int ii = 0; ii < 4; ++ii) {
    v[ii] = *(const float4*)(xr + ii * 256 + lane * 4);
    ss += v[ii].x*v[ii].x + v[ii].y*v[ii].y + v[ii].z*v[ii].z + v[ii].w*v[ii].w;
  }
  #pragma unroll
  for (int off = 32; off > 0; off >>= 1) ss += __shfl_xor(ss, off, 64);
  float rn = rsqrtf(ss);
  #pragma unroll
  for (int ii = 0; ii < 4; ++ii) {
    ushort4 o;
    o.x = f2bf(v[ii].x * rn); o.y = f2bf(v[ii].y * rn);
    o.z = f2bf(v[ii].z * rn); o.w = f2bf(v[ii].w * rn);
    *(ushort4*)(Xn + (size_t)row * DIMQ + ii * 256 + lane * 4) = o;
  }
}

// ---------------------------------------------------------------- build U ---
// 2-wave split (R5 layout) + PACKED cross-lane traffic: every shfl/exchange
// moves one u32 = (bf16 R, bf16 I) instead of two fp32 — halves the DS-pipe
// instruction count that R3-R9 showed to be the wall. xor-masks 1,2 go via
// DPP quad_perm (VALU pipe). Local arithmetic stays fp32.
// i = (h<<9)|(lane<<3)|e : h = wave parity in pair, lane bits 8:3, e bits 2:0.
__global__ __launch_bounds__(256) void build_u(const float* __restrict__ wts,
                                               unsigned int* __restrict__ Ut) {
  __shared__ unsigned int buf[2][4][64][12];   // packed; 8 used + 4 pad
  const int lane = threadIdx.x & 63;
  const int w = threadIdx.x >> 6;
  const int h = w & 1;
  const int c = blockIdx.x * 2 + (w >> 1);

  // per-lane gate table: lane g holds gate g's coefficients (g<40)
  float g0, g1, g2, g3, g4, g5, g6, g7;
  {
    const int gi = (lane < NLAYERS * NQ) ? lane : 0;
    float phi = wts[gi * 3 + 0], th = wts[gi * 3 + 1], om = wts[gi * 3 + 2];
    float ct = cosf(0.5f * th), sn = sinf(0.5f * th);
    float ap = 0.5f * (phi + om), am = 0.5f * (phi - om);
    float cp = cosf(ap), spp = sinf(ap), cm = cosf(am), sm = sinf(am);
    g0 = ct * cp;  g1 = -ct * spp;   // a
    g2 = -sn * cm; g3 = -sn * sm;    // b
    g4 = sn * cm;  g5 = -sn * sm;    // c
    g6 = ct * cp;  g7 = ct * spp;    // d
  }

  float sR[8], sI[8];
  unsigned int pP[8];                // packed partner buffer (exchanges)
  #pragma unroll
  for (int e = 0; e < 8; ++e) {
    sR[e] = (h == (c >> 9) && lane == ((c >> 3) & 63) && e == (c & 7)) ? 1.f : 0.f;
    sI[e] = 0.f;
  }
  int ev = 0;
  auto exchange = [&]() {
    unsigned int* wp = &buf[ev & 1][w][lane][0];
    uint4 o0, o1;
    o0.x = pkri(sR[0], sI[0]); o0.y = pkri(sR[1], sI[1]);
    o0.z = pkri(sR[2], sI[2]); o0.w = pkri(sR[3], sI[3]);
    o1.x = pkri(sR[4], sI[4]); o1.y = pkri(sR[5], sI[5]);
    o1.z = pkri(sR[6], sI[6]); o1.w = pkri(sR[7], sI[7]);
    *(uint4*)(wp + 0) = o0;
    *(uint4*)(wp + 4) = o1;
    __syncthreads();
    const unsigned int* rp = &buf[ev & 1][w ^ 1][lane][0];
    uint4 t0 = *(const uint4*)(rp + 0);
    uint4 t1 = *(const uint4*)(rp + 4);
    pP[0] = t0.x; pP[1] = t0.y; pP[2] = t0.z; pP[3] = t0.w;
    pP[4] = t1.x; pP[5] = t1.y; pP[6] = t1.z; pP[7] = t1.w;
    ++ev;
  };

  #pragma unroll
  for (int l = 0; l < NLAYERS; ++l) {
    #pragma unroll
    for (int q = 0; q < NQ; ++q) {
      const int gidx = l * NQ + q;
      const float G0 = RL(g0, gidx), G1 = RL(g1, gidx);
      const float G2 = RL(g2, gidx), G3 = RL(g3, gidx);
      const float G4 = RL(g4, gidx), G5 = RL(g5, gidx);
      const float G6 = RL(g6, gidx), G7 = RL(g7, gidx);
      const int p = 9 - q;                       // qubit q <-> bit p
      if (p < 3) {                               // reg bit (fp32, free)
        const int mt = 1 << p;
        #pragma unroll
        for (int e0 = 0; e0 < 8; ++e0) {
          if (e0 & mt) continue;
          const int e1 = e0 | mt;
          float r0 = sR[e0], i0 = sI[e0], r1 = sR[e1], i1 = sI[e1];
          sR[e0] = G0*r0 - G1*i0 + G2*r1 - G3*i1;
          sI[e0] = G0*i0 + G1*r0 + G2*i1 + G3*r1;
          sR[e1] = G4*r0 - G5*i0 + G6*r1 - G7*i1;
          sI[e1] = G4*i0 + G5*r0 + G6*i1 + G7*r1;
        }
      } else if (p < 9) {                        // lane bit: packed move
        const int m = 1 << (p - 3);
        const int L = (lane >> (p - 3)) & 1;
        const float aR = L ? G6 : G0, aI = L ? G7 : G1;
        const float bR = L ? G4 : G2, bI = L ? G5 : G3;
        unsigned int pk[8];
        #pragma unroll
        for (int e = 0; e < 8; ++e) pk[e] = pkri(sR[e], sI[e]);
        #pragma unroll
        for (int e = 0; e < 8; ++e) pk[e] = lmove(pk[e], m);
        #pragma unroll
        for (int e = 0; e < 8; ++e) {
          float oR = upR(pk[e]), oI = upI(pk[e]);
          float r = sR[e], i = sI[e];
          sR[e] = aR*r - aI*i + bR*oR - bI*oI;
          sI[e] = aR*i + aI*r + bR*oI + bI*oR;
        }
      } else {                                   // wave bit (p==9)
        exchange();
        const float aR = h ? G6 : G0, aI = h ? G7 : G1;
        const float bR = h ? G4 : G2, bI = h ? G5 : G3;
        #pragma unroll
        for (int e = 0; e < 8; ++e) {
          float oR = upR(pP[e]), oI = upI(pP[e]);
          float r = sR[e], i = sI[e];
          sR[e] = aR*r - aI*i + bR*oR - bI*oI;
          sI[e] = aR*i + aI*r + bR*oI + bI*oR;
        }
      }
    }
    const int r = l % (NQ - 1) + 1;
    #pragma unroll
    for (int q = 0; q < NQ; ++q) {
      const int pc = 9 - q, pt = 9 - ((q + r) % NQ);
      if (pt == 9) {                             // target = wave bit: exchange
        exchange();
        if (pc < 3) {
          #pragma unroll
          for (int e = 0; e < 8; ++e)
            if ((e >> pc) & 1) { sR[e] = upR(pP[e]); sI[e] = upI(pP[e]); }
        } else {
          const int ctl = (lane >> (pc - 3)) & 1;
          #pragma unroll
          for (int e = 0; e < 8; ++e) {
            sR[e] = ctl ? upR(pP[e]) : sR[e];
            sI[e] = ctl ? upI(pP[e]) : sI[e];
          }
        }
      } else if (pc == 9) {                      // control = wave bit (uniform)
        if (pt < 3) {
          if (h) {
            #pragma unroll
            for (int e = 0; e < 8; ++e)
              if (((e >> pt) & 1) == 0) {
                const int e2 = e | (1 << pt);
                float tr = sR[e]; sR[e] = sR[e2]; sR[e2] = tr;
                float ti = sI[e]; sI[e] = sI[e2]; sI[e2] = ti;
              }
          }
        } else {
          const int m = 1 << (pt - 3);
          if (h) {                               // wave-uniform branch
            #pragma unroll
            for (int e = 0; e < 8; ++e) {
              unsigned int pk = lmove(pkri(sR[e], sI[e]), m);
              sR[e] = upR(pk); sI[e] = upI(pk);
            }
          }
        }
      } else if (pc < 3 && pt < 3) {             // rr (fp32, free)
        #pragma unroll
        for (int e = 0; e < 8; ++e)
          if (((e >> pc) & 1) && !((e >> pt) & 1)) {
            const int e2 = e | (1 << pt);
            float tr = sR[e]; sR[e] = sR[e2]; sR[e2] = tr;
            float ti = sI[e]; sI[e] = sI[e2]; sI[e2] = ti;
          }
      } else if (pc >= 3 && pt < 3) {            // lane ctl, reg tgt (free)
        const int ctl = (lane >> (pc - 3)) & 1;
        #pragma unroll
        for (int e0 = 0; e0 < 8; ++e0) {
          if (e0 & (1 << pt)) continue;
          const int e1 = e0 | (1 << pt);
          float r0 = sR[e0], i0 = sI[e0], r1 = sR[e1], i1 = sI[e1];
          sR[e0] = ctl ? r1 : r0;  sI[e0] = ctl ? i1 : i0;
          sR[e1] = ctl ? r0 : r1;  sI[e1] = ctl ? i0 : i1;
        }
      } else if (pc < 3 && pt >= 3) {            // reg ctl, lane tgt: packed
        const int m = 1 << (pt - 3);
        #pragma unroll
        for (int e = 0; e < 8; ++e)
          if ((e >> pc) & 1) {
            unsigned int pk = lmove(pkri(sR[e], sI[e]), m);
            sR[e] = upR(pk); sI[e] = upI(pk);
          }
      } else {                                   // lane ctl, lane tgt: packed
        const int m = 1 << (pt - 3);
        const int ctl = (lane >> (pc - 3)) & 1;
        #pragma unroll
        for (int e = 0; e < 8; ++e) {
          unsigned int pk = lmove(pkri(sR[e], sI[e]), m);
          sR[e] = ctl ? upR(pk) : sR[e];
          sI[e] = ctl ? upI(pk) : sI[e];
        }
      }
    }
  }

  // coalesced: Ut[c][i] = pack(bf16 R, bf16 I), i = (h<<9)|(lane<<3)|e
  unsigned int* rowp = Ut + (size_t)c * 1024 + (h << 9) + (lane << 3);
  #pragma unroll
  for (int g4 = 0; g4 < 2; ++g4) {
    uint4 o;
    o.x = (unsigned)f2bf(sR[g4*4+0]) | ((unsigned)f2bf(sI[g4*4+0]) << 16);
    o.y = (unsigned)f2bf(sR[g4*4+1]) | ((unsigned)f2bf(sI[g4*4+1]) << 16);
    o.z = (unsigned)f2bf(sR[g4*4+2]) | ((unsigned)f2bf(sI[g4*4+2]) << 16);
    o.w = (unsigned)f2bf(sR[g4*4+3]) | ((unsigned)f2bf(sI[g4*4+3]) << 16);
    *(uint4*)(rowp + g4 * 4) = o;
  }
}

// ------------------------------------------------------------- transpose ---
__global__ __launch_bounds__(256) void transpose_u(const unsigned int* __restrict__ Ut,
                                                   unsigned short* __restrict__ Ub) {
  __shared__ unsigned int T[64][65];
  const int t = threadIdx.x;
  const int I0 = (blockIdx.x & 15) * 64;
  const int C0 = (blockIdx.x >> 4) * 64;
  {
    const int cr = t >> 2, ib = (t & 3) * 16;
    const unsigned int* src = Ut + (size_t)(C0 + cr) * 1024 + I0 + ib;
    #pragma unroll
    for (int g4 = 0; g4 < 4; ++g4) {
      uint4 v = *(const uint4*)(src + g4 * 4);
      T[ib + g4*4 + 0][cr] = v.x;
      T[ib + g4*4 + 1][cr] = v.y;
      T[ib + g4*4 + 2][cr] = v.z;
      T[ib + g4*4 + 3][cr] = v.w;
    }
  }
  __syncthreads();
  {
    const int il = t >> 2, cb = (t & 3) * 16;
    union { unsigned short u16[16]; uint4 q[2]; } LO, HI;
    #pragma unroll
    for (int k = 0; k < 16; ++k) {
      unsigned int u = T[il][cb + k];
      LO.u16[k] = (unsigned short)(u & 0xffffu);
      HI.u16[k] = (unsigned short)(u >> 16);
    }
    unsigned short* d0 = Ub + (size_t)(2 * (I0 + il)) * DIMQ + C0 + cb;
    unsigned short* d1 = d0 + DIMQ;
    *(uint4*)(d0 + 0) = LO.q[0];
    *(uint4*)(d0 + 8) = LO.q[1];
    *(uint4*)(d1 + 0) = HI.q[0];
    *(uint4*)(d1 + 8) = HI.q[1];
  }
}

// ----------------------------------------------------- GEMM + z-partials ---
__device__ __forceinline__ void gload_lds16(const void* g, void* lds) {
  __builtin_amdgcn_global_load_lds(
      (const __attribute__((address_space(1))) unsigned int*)g,
      (__attribute__((address_space(3))) unsigned int*)lds, 16, 0, 0);
}

__global__ __launch_bounds__(256, 3) void gemm_bt(const unsigned short* __restrict__ A,
                                                  const unsigned short* __restrict__ B,
                                                  float* __restrict__ Zp) {
  __shared__ char lds[32768];
  char* As = lds;
  char* Bs = lds + 16384;
  int tid = threadIdx.x;
  int lane = tid & 63;
  int w = tid >> 6;
  int mtile = blockIdx.x & 31;
  int ntile = blockIdx.x >> 5;
  int wm = (w & 1) * 64;
  int wn = (w >> 1) * 64;
  const unsigned short* Ag = A + (size_t)mtile * 128 * GK;
  const unsigned short* Bg = B + (size_t)ntile * 128 * GK;
  f32x4 acc[4][4];
  #pragma unroll
  for (int i = 0; i < 4; ++i)
    #pragma unroll
    for (int j = 0; j < 4; ++j) acc[i][j] = (f32x4){0.f, 0.f, 0.f, 0.f};

  for (int kt = 0; kt < GK; kt += 64) {
    __syncthreads();
    #pragma unroll
    for (int s = 0; s < 4; ++s) {
      int chunk = (w << 8) | (s << 6) | lane;
      int row = chunk >> 3, ch = chunk & 7;
      int sch = ch ^ (row & 7);
      gload_lds16(Ag + (size_t)row * GK + kt + sch * 8, As + (((w << 2) + s) << 10));
      gload_lds16(Bg + (size_t)row * GK + kt + sch * 8, Bs + (((w << 2) + s) << 10));
    }
    __builtin_amdgcn_s_waitcnt(0);
    __syncthreads();
    #pragma unroll
    for (int ks = 0; ks < 2; ++ks) {
      s16x8 af[4], bfr[4];
      #pragma unroll
      for (int mt = 0; mt < 4; ++mt) {
        int rowa = wm + mt * 16 + (lane & 15);
        int kc = (ks << 2) + (lane >> 4);
        af[mt] = *(const s16x8*)(As + (((rowa << 3) + (kc ^ (rowa & 7))) << 4));
        int rowb = wn + mt * 16 + (lane & 15);
        bfr[mt] = *(const s16x8*)(Bs + (((rowb << 3) + (kc ^ (rowb & 7))) << 4));
      }
      #pragma unroll
      for (int mt = 0; mt < 4; ++mt)
        #pragma unroll
        for (int nt = 0; nt < 4; ++nt)
          acc[mt][nt] = __builtin_amdgcn_mfma_f32_16x16x32_bf16(af[mt], bfr[nt],
                                                                acc[mt][nt], 0, 0, 0);
    }
  }

  // ---- epilogue: Walsh-Hadamard z-partials (no Y materialization) ----
  const int quad = lane >> 4, cn = lane & 15;
  float* zb = Zp + (size_t)(blockIdx.x * 4 + w) * 6 * 64;
  #pragma unroll
  for (int mt = 0; mt < 4; ++mt) {
    #pragma unroll
    for (int r = 0; r < 4; ++r) {
      float p0 = acc[mt][0][r] * acc[mt][0][r];
      float p1 = acc[mt][1][r] * acc[mt][1][r];
      float p2 = acc[mt][2][r] * acc[mt][2][r];
      float p3 = acc[mt][3][r] * acc[mt][3][r];
      float ca = p0 + p1 + p2 + p3;
      float c3 = p0 - p1 + p2 - p3;              // i bit3 (= nt bit0)
      float c4 = p0 + p1 - p2 - p3;              // i bit4 (= nt bit1)
      #pragma unroll
      for (int m = 1; m <= 8; m <<= 1) {
        float o = __shfl_xor(ca, m, 64);
        ca = (lane & m) ? (o - ca) : (ca + o);   // WHT stage
        c3 += __shfl_xor(c3, m, 64);             // plain sum
        c4 += __shfl_xor(c4, m, 64);
      }
      int rloc = mt * 16 + quad * 4 + r;
      if (cn == 0) {
        zb[5 * 64 + rloc] = ca;                  // W_0: unsigned sum
        zb[3 * 64 + rloc] = c3;
        zb[4 * 64 + rloc] = c4;
      } else if (cn == 2) {
        zb[0 * 64 + rloc] = ca;                  // W_2: i bit0
      } else if (cn == 4) {
        zb[1 * 64 + rloc] = ca;                  // W_4: i bit1
      } else if (cn == 8) {
        zb[2 * 64 + rloc] = ca;                  // W_8: i bit2
      }
    }
  }
}

// -------------------------------------------------------------- finalize ---
__global__ __launch_bounds__(256) void finalize(const float* __restrict__ Zp,
                                                const float* __restrict__ W,
                                                const float* __restrict__ bias,
                                                float* __restrict__ out) {
  int rg = blockIdx.x * 256 + threadIdx.x;      // 0..4095
  int mtile = rg >> 7;
  int rl = rg & 127;
  int wlo = rl >> 6;                            // wave low bit (wm)
  int rloc = rl & 63;
  float z[10];
  #pragma unroll
  for (int q = 0; q < 10; ++q) z[q] = 0.f;
  for (int ntile = 0; ntile < 16; ++ntile) {
    int bid = ntile * 32 + mtile;
    #pragma unroll
    for (int wn = 0; wn < 2; ++wn) {
      int w = (wn << 1) | wlo;
      const float* P = Zp + (size_t)(bid * 4 + w) * 6 * 64 + rloc;
      z[9] += P[0];
      z[8] += P[64];
      z[7] += P[128];
      z[6] += P[192];
      z[5] += P[256];
      float pa = P[320];
      z[4] += wn ? -pa : pa;                    // i bit5
      z[3] += (ntile & 1) ? -pa : pa;           // bit6
      z[2] += (ntile & 2) ? -pa : pa;           // bit7
      z[1] += (ntile & 4) ? -pa : pa;           // bit8
      z[0] += (ntile & 8) ? -pa : pa;           // bit9
    }
  }
  #pragma unroll
  for (int o = 0; o < NOUT; ++o) {
    float a = bias[o];
    #pragma unroll
    for (int q = 0; q < 10; ++q) a += z[q] * W[o * 10 + q];
    out[(size_t)rg * NOUT + o] = a;
  }
}

extern "C" void kernel_launch(void* const* d_in, const int* in_sizes, int n_in,
                              void* d_out, int out_size, void* d_ws, size_t ws_size,
                              hipStream_t stream) {
  const float* X    = (const float*)d_in[0];
  const float* wts  = (const float*)d_in[1];
  const float* W    = (const float*)d_in[2];
  const float* bias = (const float*)d_in[3];
  float* out = (float*)d_out;
  char* ws = (char*)d_ws;
  unsigned short* Xn = (unsigned short*)ws;                       // 8 MB
  unsigned short* Ub = (unsigned short*)(ws + 8u  * 1024 * 1024); // 4 MB
  unsigned int* Ut   = (unsigned int*)(ws + 12u * 1024 * 1024);   // 4 MB
  float* Zp          = (float*)(ws + 16u * 1024 * 1024);          // 3 MB

  hipLaunchKernelGGL(build_u,        dim3(DIMQ / 2),  dim3(256), 0, stream, wts, Ut);
  hipLaunchKernelGGL(normalize_rows, dim3(BATCH / 4), dim3(256), 0, stream, X, Xn);
  hipLaunchKernelGGL(transpose_u,    dim3(256),       dim3(256), 0, stream, Ut, Ub);
  hipLaunchKernelGGL(gemm_bt,        dim3((GM/128)*(GN/128)), dim3(256), 0, stream, Xn, Ub, Zp);
  hipLaunchKernelGGL(finalize,       dim3(BATCH / 256), dim3(256), 0, stream, Zp, W, bias, out);
}